// Round 1
// baseline (295.674 us; speedup 1.0000x reference)
//
#include <hip/hip_runtime.h>

#define NN 50000
#define NE 800000
// K=8, D_IN=64, D_OUT=64 hard-coded below

__global__ void k_init(float* __restrict__ deg, int* __restrict__ cnt,
                       int* __restrict__ cursor, int n) {
    int i = blockIdx.x * blockDim.x + threadIdx.x;
    if (i < n) { deg[i] = 1.0f; cnt[i] = 0; cursor[i] = 0; }
}

__global__ void k_hist(const int* __restrict__ ei, const float* __restrict__ ew,
                       float* __restrict__ deg, int* __restrict__ cnt, int E) {
    int e = blockIdx.x * blockDim.x + threadIdx.x;
    if (e < E) {
        int d = ei[E + e];
        atomicAdd(&deg[d], ew[e]);
        atomicAdd(&cnt[d], 1);
    }
}

// Single block, 1024 threads. Exclusive scan of cnt -> row_ptr, and
// dinv = rsqrt(deg) written in-place over deg.
__global__ void k_scan(const int* __restrict__ cnt, float* __restrict__ deg_dinv,
                       int* __restrict__ row_ptr, int n) {
    __shared__ int wsum[16];
    __shared__ int woff[16];
    __shared__ int stot;
    int tid  = threadIdx.x;
    int lane = tid & 63;
    int wid  = tid >> 6;
    int run = 0;
    for (int base = 0; base < n; base += 4096) {
        int i0 = base + tid * 4;
        int v[4];
#pragma unroll
        for (int j = 0; j < 4; j++) {
            int i = i0 + j;
            v[j] = 0;
            if (i < n) {
                v[j] = cnt[i];
                deg_dinv[i] = rsqrtf(deg_dinv[i]);   // deg >= 1 always
            }
        }
        int s = v[0] + v[1] + v[2] + v[3];
        int incl = s;
#pragma unroll
        for (int off = 1; off < 64; off <<= 1) {
            int t = __shfl_up(incl, off, 64);
            if (lane >= off) incl += t;
        }
        if (lane == 63) wsum[wid] = incl;
        __syncthreads();
        if (tid == 0) {
            int a = 0;
            for (int w = 0; w < 16; w++) { woff[w] = a; a += wsum[w]; }
            stot = a;
        }
        __syncthreads();
        int excl = run + woff[wid] + (incl - s);
#pragma unroll
        for (int j = 0; j < 4; j++) {
            int i = i0 + j;
            if (i < n) row_ptr[i] = excl;
            excl += v[j];
        }
        run += stot;
        __syncthreads();   // protect wsum/stot before next chunk
    }
    if (tid == 0) row_ptr[n] = run;
}

__global__ void k_scatter(const int* __restrict__ ei, const float* __restrict__ ew,
                          const float* __restrict__ dinv, const int* __restrict__ row_ptr,
                          int* __restrict__ cursor, int2* __restrict__ sorted, int E) {
    int e = blockIdx.x * blockDim.x + threadIdx.x;
    if (e < E) {
        int s = ei[e];
        int d = ei[E + e];
        float nrm = dinv[s] * ew[e] * dinv[d];
        int pos = row_ptr[d] + atomicAdd(&cursor[d], 1);
        sorted[pos] = make_int2(s, __float_as_int(nrm));
    }
}

// One wave per node; lane = channel. xagg[n,:] = dinv^2 * x[n,:] + sum norm*x[src,:]
__global__ void k_agg(const float* __restrict__ x, const float* __restrict__ dinv,
                      const int* __restrict__ row_ptr, const int2* __restrict__ sorted,
                      float* __restrict__ xagg, int n) {
    int node = blockIdx.x * 4 + (threadIdx.x >> 6);
    if (node >= n) return;
    int lane = threadIdx.x & 63;
    float di = dinv[node];
    float acc = di * di * x[(size_t)node * 64 + lane];
    int beg = row_ptr[node], end = row_ptr[node + 1];
    for (int i = beg; i < end; ++i) {
        int2 p = sorted[i];
        acc += __int_as_float(p.y) * x[(size_t)p.x * 64 + lane];
    }
    xagg[(size_t)node * 64 + lane] = acc;
}

// out[n,k,:] = xagg[n,:] @ W[k] + b[k].  16 nodes per 128-thread block,
// register-blocked over nodes; float4 W loads and float4 output stores.
__global__ __launch_bounds__(128) void k_gemm(const float* __restrict__ xagg,
                                              const float4* __restrict__ W4,
                                              const float4* __restrict__ b4,
                                              float4* __restrict__ out4, int n) {
    __shared__ float xs[16][64];
    int t  = threadIdx.x;          // 0..127
    int n0 = blockIdx.x * 16;
    const float4* xg = (const float4*)(xagg + (size_t)n0 * 64);
    float4* xsv = (float4*)&xs[0][0];
    xsv[t]       = xg[t];
    xsv[t + 128] = xg[t + 128];
    __syncthreads();
    int k = t >> 4;       // 0..7
    int q = t & 15;       // output float4 column within head
    float4 bias = b4[k * 16 + q];
    float4 acc[16];
#pragma unroll
    for (int nn = 0; nn < 16; nn++) acc[nn] = bias;
    for (int c = 0; c < 64; c++) {
        float4 w = W4[(size_t)k * 1024 + c * 16 + q];
#pragma unroll
        for (int nn = 0; nn < 16; nn++) {
            float a = xs[nn][c];
            acc[nn].x += a * w.x;
            acc[nn].y += a * w.y;
            acc[nn].z += a * w.z;
            acc[nn].w += a * w.w;
        }
    }
#pragma unroll
    for (int nn = 0; nn < 16; nn++) {
        out4[((size_t)(n0 + nn) * 8 + k) * 16 + q] = acc[nn];
    }
}

extern "C" void kernel_launch(void* const* d_in, const int* in_sizes, int n_in,
                              void* d_out, int out_size, void* d_ws, size_t ws_size,
                              hipStream_t stream) {
    const float* x  = (const float*)d_in[0];
    const int*   ei = (const int*)d_in[1];     // [2, E] int32: src row then dst row
    const float* ew = (const float*)d_in[2];
    const float* W  = (const float*)d_in[3];   // [8,64,64]
    const float* b  = (const float*)d_in[4];   // [8,64]
    float* out = (float*)d_out;

    char* ws = (char*)d_ws;
    size_t off = 0;
    auto carve = [&](size_t bytes) {
        void* p = ws + off;
        off += (bytes + 255) & ~(size_t)255;
        return p;
    };
    float* deg     = (float*)carve((size_t)NN * 4);        // becomes dinv in-place
    int*   cnt     = (int*)  carve((size_t)NN * 4);
    int*   row_ptr = (int*)  carve((size_t)(NN + 1) * 4);
    int*   cursor  = (int*)  carve((size_t)NN * 4);
    int2*  sorted  = (int2*) carve((size_t)NE * 8);
    float* xagg    = (float*)carve((size_t)NN * 64 * 4);
    (void)ws_size; (void)in_sizes; (void)n_in; (void)out_size;

    k_init<<<(NN + 255) / 256, 256, 0, stream>>>(deg, cnt, cursor, NN);
    k_hist<<<(NE + 255) / 256, 256, 0, stream>>>(ei, ew, deg, cnt, NE);
    k_scan<<<1, 1024, 0, stream>>>(cnt, deg, row_ptr, NN);
    k_scatter<<<(NE + 255) / 256, 256, 0, stream>>>(ei, ew, deg, row_ptr, cursor, sorted, NE);
    k_agg<<<(NN + 3) / 4, 256, 0, stream>>>(x, deg, row_ptr, sorted, xagg, NN);
    k_gemm<<<NN / 16, 128, 0, stream>>>(xagg, (const float4*)W, (const float4*)b,
                                        (float4*)out, NN);
}

// Round 3
// 262.151 us; speedup vs baseline: 1.1279x; 1.1279x over previous
//
#include <hip/hip_runtime.h>

#define NN 50000
#define NE 800000
// K=8, D_IN=64, D_OUT=64 hard-coded below

typedef float v4f __attribute__((ext_vector_type(4)));

__global__ void k_init(float* __restrict__ deg, int* __restrict__ cnt,
                       int* __restrict__ cursor, int n) {
    int i = blockIdx.x * blockDim.x + threadIdx.x;
    if (i < n) { deg[i] = 1.0f; cnt[i] = 0; cursor[i] = 0; }
}

__global__ void k_hist(const int* __restrict__ ei, const float* __restrict__ ew,
                       float* __restrict__ deg, int* __restrict__ cnt, int E) {
    int e = blockIdx.x * blockDim.x + threadIdx.x;
    if (e < E) {
        int d = ei[E + e];
        atomicAdd(&deg[d], ew[e]);
        atomicAdd(&cnt[d], 1);
    }
}

// Single block, 1024 threads. Exclusive scan of cnt -> row_ptr, and
// dinv = rsqrt(deg) written in-place over deg.
__global__ void k_scan(const int* __restrict__ cnt, float* __restrict__ deg_dinv,
                       int* __restrict__ row_ptr, int n) {
    __shared__ int wsum[16];
    __shared__ int woff[16];
    __shared__ int stot;
    int tid  = threadIdx.x;
    int lane = tid & 63;
    int wid  = tid >> 6;
    int run = 0;
    for (int base = 0; base < n; base += 4096) {
        int i0 = base + tid * 4;
        int v[4];
#pragma unroll
        for (int j = 0; j < 4; j++) {
            int i = i0 + j;
            v[j] = 0;
            if (i < n) {
                v[j] = cnt[i];
                deg_dinv[i] = rsqrtf(deg_dinv[i]);   // deg >= 1 always
            }
        }
        int s = v[0] + v[1] + v[2] + v[3];
        int incl = s;
#pragma unroll
        for (int off = 1; off < 64; off <<= 1) {
            int t = __shfl_up(incl, off, 64);
            if (lane >= off) incl += t;
        }
        if (lane == 63) wsum[wid] = incl;
        __syncthreads();
        if (tid == 0) {
            int a = 0;
            for (int w = 0; w < 16; w++) { woff[w] = a; a += wsum[w]; }
            stot = a;
        }
        __syncthreads();
        int excl = run + woff[wid] + (incl - s);
#pragma unroll
        for (int j = 0; j < 4; j++) {
            int i = i0 + j;
            if (i < n) row_ptr[i] = excl;
            excl += v[j];
        }
        run += stot;
        __syncthreads();   // protect wsum/stot before next chunk
    }
    if (tid == 0) row_ptr[n] = run;
}

__global__ void k_scatter(const int* __restrict__ ei, const float* __restrict__ ew,
                          const float* __restrict__ dinv, const int* __restrict__ row_ptr,
                          int* __restrict__ cursor, int2* __restrict__ sorted, int E) {
    int e = blockIdx.x * blockDim.x + threadIdx.x;
    if (e < E) {
        int s = ei[e];
        int d = ei[E + e];
        float nrm = dinv[s] * ew[e] * dinv[d];
        int pos = row_ptr[d] + atomicAdd(&cursor[d], 1);
        sorted[pos] = make_int2(s, __float_as_int(nrm));
    }
}

// One wave per node; lane = channel. xagg[n,:] = dinv^2 * x[n,:] + sum norm*x[src,:]
// 8-deep predicated unroll: 8 edge-record loads then 8 independent row gathers
// in flight per iteration -> breaks the serial dependent-load chain.
__global__ __launch_bounds__(256) void k_agg(const float* __restrict__ x,
                                             const float* __restrict__ dinv,
                                             const int* __restrict__ row_ptr,
                                             const int2* __restrict__ sorted,
                                             float* __restrict__ xagg, int n) {
    int node = blockIdx.x * 4 + (threadIdx.x >> 6);
    if (node >= n) return;
    int lane = threadIdx.x & 63;
    float di = dinv[node];
    float a[8];
    a[0] = di * di * x[((unsigned)node << 6) + lane];
#pragma unroll
    for (int j = 1; j < 8; j++) a[j] = 0.f;
    int beg = row_ptr[node], end = row_ptr[node + 1];
    for (int i = beg; i < end; i += 8) {
        int   si[8];
        float w[8];
#pragma unroll
        for (int j = 0; j < 8; j++) {
            int idx = (i + j < end) ? (i + j) : beg;   // safe clamp (beg<end here)
            int2 p = sorted[idx];
            si[j] = p.x;
            w[j]  = (i + j < end) ? __int_as_float(p.y) : 0.f;
        }
#pragma unroll
        for (int j = 0; j < 8; j++) {
            a[j] += w[j] * x[((unsigned)si[j] << 6) + lane];
        }
    }
    float acc = ((a[0] + a[1]) + (a[2] + a[3])) + ((a[4] + a[5]) + (a[6] + a[7]));
    xagg[((unsigned)node << 6) + lane] = acc;
}

// out[n,k,:] = xagg[n,:] @ W[k] + b[k].  16 nodes per 128-thread block,
// register-blocked over nodes; float4 W loads, non-temporal output stores
// (output stream is never re-read -> don't pollute L2).
__global__ __launch_bounds__(128) void k_gemm(const float* __restrict__ xagg,
                                              const float4* __restrict__ W4,
                                              const float4* __restrict__ b4,
                                              float* __restrict__ out, int n) {
    __shared__ float xs[16][64];
    int t  = threadIdx.x;          // 0..127
    int n0 = blockIdx.x * 16;
    const float4* xg = (const float4*)(xagg + (size_t)n0 * 64);
    float4* xsv = (float4*)&xs[0][0];
    xsv[t]       = xg[t];
    xsv[t + 128] = xg[t + 128];
    __syncthreads();
    int k = t >> 4;       // 0..7
    int q = t & 15;       // output float4 column within head
    float4 bias = b4[k * 16 + q];
    float4 acc[16];
#pragma unroll
    for (int nn = 0; nn < 16; nn++) acc[nn] = bias;
    for (int c = 0; c < 64; c++) {
        float4 w = W4[(size_t)k * 1024 + c * 16 + q];
#pragma unroll
        for (int nn = 0; nn < 16; nn++) {
            float a = xs[nn][c];
            acc[nn].x += a * w.x;
            acc[nn].y += a * w.y;
            acc[nn].z += a * w.z;
            acc[nn].w += a * w.w;
        }
    }
#pragma unroll
    for (int nn = 0; nn < 16; nn++) {
        v4f v = { acc[nn].x, acc[nn].y, acc[nn].z, acc[nn].w };
        v4f* dst = (v4f*)(out + (((size_t)(n0 + nn) * 8 + k) * 16 + q) * 4);
        __builtin_nontemporal_store(v, dst);
    }
}

extern "C" void kernel_launch(void* const* d_in, const int* in_sizes, int n_in,
                              void* d_out, int out_size, void* d_ws, size_t ws_size,
                              hipStream_t stream) {
    const float* x  = (const float*)d_in[0];
    const int*   ei = (const int*)d_in[1];     // [2, E] int32: src row then dst row
    const float* ew = (const float*)d_in[2];
    const float* W  = (const float*)d_in[3];   // [8,64,64]
    const float* b  = (const float*)d_in[4];   // [8,64]
    float* out = (float*)d_out;

    char* ws = (char*)d_ws;
    size_t off = 0;
    auto carve = [&](size_t bytes) {
        void* p = ws + off;
        off += (bytes + 255) & ~(size_t)255;
        return p;
    };
    float* deg     = (float*)carve((size_t)NN * 4);        // becomes dinv in-place
    int*   cnt     = (int*)  carve((size_t)NN * 4);
    int*   row_ptr = (int*)  carve((size_t)(NN + 1) * 4);
    int*   cursor  = (int*)  carve((size_t)NN * 4);
    int2*  sorted  = (int2*) carve((size_t)NE * 8);
    float* xagg    = (float*)carve((size_t)NN * 64 * 4);
    (void)ws_size; (void)in_sizes; (void)n_in; (void)out_size;

    k_init<<<(NN + 255) / 256, 256, 0, stream>>>(deg, cnt, cursor, NN);
    k_hist<<<(NE + 255) / 256, 256, 0, stream>>>(ei, ew, deg, cnt, NE);
    k_scan<<<1, 1024, 0, stream>>>(cnt, deg, row_ptr, NN);
    k_scatter<<<(NE + 255) / 256, 256, 0, stream>>>(ei, ew, deg, row_ptr, cursor, sorted, NE);
    k_agg<<<(NN + 3) / 4, 256, 0, stream>>>(x, deg, row_ptr, sorted, xagg, NN);
    k_gemm<<<NN / 16, 128, 0, stream>>>(xagg, (const float4*)W, (const float4*)b,
                                        out, NN);
}

// Round 4
// 197.421 us; speedup vs baseline: 1.4977x; 1.3279x over previous
//
#include <hip/hip_runtime.h>

#define NN 50000
#define NE 800000
// K=8, D_IN=64, D_OUT=64 hard-coded below

typedef float v4f __attribute__((ext_vector_type(4)));
typedef unsigned long long u64;

#define FXS 33554432.0f          // 2^25 fixed-point scale for edge weights
#define FXI (1.0f / 33554432.0f)

// One packed u64 atomic per edge: bits [40..63] = count, bits [0..39] = sum(ew)
// in 2^-25 fixed point (max node weight-sum ~50 << 2^15, no overflow).
// Return value gives this edge's position within its dst group -> no cursor
// atomic needed in k_scatter.
__global__ void k_hist(const int* __restrict__ ei, const float* __restrict__ ew,
                       u64* __restrict__ hist, unsigned* __restrict__ posbuf, int E) {
    int e = blockIdx.x * blockDim.x + threadIdx.x;
    if (e < E) {
        int d = ei[E + e];
        unsigned fx = (unsigned)(ew[e] * FXS + 0.5f);
        u64 old = atomicAdd(&hist[d], ((u64)1 << 40) | (u64)fx);
        posbuf[e] = (unsigned)(old >> 40);
    }
}

// Single block, 1024 threads. Exclusive scan of counts -> row_ptr, and
// dinv = rsqrt(1 + fixed_point_sum) (self-loop weight 1 folded in here).
__global__ void k_scan(const u64* __restrict__ hist, float* __restrict__ dinv,
                       int* __restrict__ row_ptr, int n) {
    __shared__ int wsum[16];
    __shared__ int woff[16];
    __shared__ int stot;
    int tid  = threadIdx.x;
    int lane = tid & 63;
    int wid  = tid >> 6;
    int run = 0;
    for (int base = 0; base < n; base += 4096) {
        int i0 = base + tid * 4;
        int v[4];
#pragma unroll
        for (int j = 0; j < 4; j++) {
            int i = i0 + j;
            v[j] = 0;
            if (i < n) {
                u64 h = hist[i];
                v[j] = (int)(h >> 40);
                float deg = 1.0f + (float)(h & 0xFFFFFFFFFFULL) * FXI;
                dinv[i] = rsqrtf(deg);
            }
        }
        int s = v[0] + v[1] + v[2] + v[3];
        int incl = s;
#pragma unroll
        for (int off = 1; off < 64; off <<= 1) {
            int t = __shfl_up(incl, off, 64);
            if (lane >= off) incl += t;
        }
        if (lane == 63) wsum[wid] = incl;
        __syncthreads();
        if (tid == 0) {
            int a = 0;
            for (int w = 0; w < 16; w++) { woff[w] = a; a += wsum[w]; }
            stot = a;
        }
        __syncthreads();
        int excl = run + woff[wid] + (incl - s);
#pragma unroll
        for (int j = 0; j < 4; j++) {
            int i = i0 + j;
            if (i < n) row_ptr[i] = excl;
            excl += v[j];
        }
        run += stot;
        __syncthreads();   // protect wsum/stot before next chunk
    }
    if (tid == 0) row_ptr[n] = run;
}

// Atomic-free scatter: position comes from k_hist's atomic return value.
__global__ void k_scatter(const int* __restrict__ ei, const float* __restrict__ ew,
                          const float* __restrict__ dinv, const int* __restrict__ row_ptr,
                          const unsigned* __restrict__ posbuf,
                          int2* __restrict__ sorted, int E) {
    int e = blockIdx.x * blockDim.x + threadIdx.x;
    if (e < E) {
        int s = ei[e];
        int d = ei[E + e];
        float nrm = dinv[s] * ew[e] * dinv[d];
        int pos = row_ptr[d] + (int)posbuf[e];
        sorted[pos] = make_int2(s, __float_as_int(nrm));
    }
}

// One wave per node; lane = channel. xagg[n,:] = dinv^2 * x[n,:] + sum norm*x[src,:]
// 8-deep predicated unroll: 8 edge-record loads then 8 independent row gathers
// in flight per iteration -> breaks the serial dependent-load chain.
__global__ __launch_bounds__(256) void k_agg(const float* __restrict__ x,
                                             const float* __restrict__ dinv,
                                             const int* __restrict__ row_ptr,
                                             const int2* __restrict__ sorted,
                                             float* __restrict__ xagg, int n) {
    int node = blockIdx.x * 4 + (threadIdx.x >> 6);
    if (node >= n) return;
    int lane = threadIdx.x & 63;
    float di = dinv[node];
    float a[8];
    a[0] = di * di * x[((unsigned)node << 6) + lane];
#pragma unroll
    for (int j = 1; j < 8; j++) a[j] = 0.f;
    int beg = row_ptr[node], end = row_ptr[node + 1];
    for (int i = beg; i < end; i += 8) {
        int   si[8];
        float w[8];
#pragma unroll
        for (int j = 0; j < 8; j++) {
            int idx = (i + j < end) ? (i + j) : beg;   // safe clamp (beg<end here)
            int2 p = sorted[idx];
            si[j] = p.x;
            w[j]  = (i + j < end) ? __int_as_float(p.y) : 0.f;
        }
#pragma unroll
        for (int j = 0; j < 8; j++) {
            a[j] += w[j] * x[((unsigned)si[j] << 6) + lane];
        }
    }
    float acc = ((a[0] + a[1]) + (a[2] + a[3])) + ((a[4] + a[5]) + (a[6] + a[7]));
    xagg[((unsigned)node << 6) + lane] = acc;
}

// out[n,k,:] = xagg[n,:] @ W[k] + b[k].  16 nodes per 128-thread block,
// register-blocked over nodes; float4 W loads, non-temporal output stores
// (output stream is never re-read -> don't pollute L2).
__global__ __launch_bounds__(128) void k_gemm(const float* __restrict__ xagg,
                                              const float4* __restrict__ W4,
                                              const float4* __restrict__ b4,
                                              float* __restrict__ out, int n) {
    __shared__ float xs[16][64];
    int t  = threadIdx.x;          // 0..127
    int n0 = blockIdx.x * 16;
    const float4* xg = (const float4*)(xagg + (size_t)n0 * 64);
    float4* xsv = (float4*)&xs[0][0];
    xsv[t]       = xg[t];
    xsv[t + 128] = xg[t + 128];
    __syncthreads();
    int k = t >> 4;       // 0..7
    int q = t & 15;       // output float4 column within head
    float4 bias = b4[k * 16 + q];
    float4 acc[16];
#pragma unroll
    for (int nn = 0; nn < 16; nn++) acc[nn] = bias;
    for (int c = 0; c < 64; c++) {
        float4 w = W4[(size_t)k * 1024 + c * 16 + q];
#pragma unroll
        for (int nn = 0; nn < 16; nn++) {
            float a = xs[nn][c];
            acc[nn].x += a * w.x;
            acc[nn].y += a * w.y;
            acc[nn].z += a * w.z;
            acc[nn].w += a * w.w;
        }
    }
#pragma unroll
    for (int nn = 0; nn < 16; nn++) {
        v4f v = { acc[nn].x, acc[nn].y, acc[nn].z, acc[nn].w };
        v4f* dst = (v4f*)(out + (((size_t)(n0 + nn) * 8 + k) * 16 + q) * 4);
        __builtin_nontemporal_store(v, dst);
    }
}

extern "C" void kernel_launch(void* const* d_in, const int* in_sizes, int n_in,
                              void* d_out, int out_size, void* d_ws, size_t ws_size,
                              hipStream_t stream) {
    const float* x  = (const float*)d_in[0];
    const int*   ei = (const int*)d_in[1];     // [2, E] int32: src row then dst row
    const float* ew = (const float*)d_in[2];
    const float* W  = (const float*)d_in[3];   // [8,64,64]
    const float* b  = (const float*)d_in[4];   // [8,64]
    float* out = (float*)d_out;

    char* ws = (char*)d_ws;
    size_t off = 0;
    auto carve = [&](size_t bytes) {
        void* p = ws + off;
        off += (bytes + 255) & ~(size_t)255;
        return p;
    };
    u64*      hist    = (u64*)     carve((size_t)NN * 8);
    unsigned* posbuf  = (unsigned*)carve((size_t)NE * 4);
    float*    dinv    = (float*)   carve((size_t)NN * 4);
    int*      row_ptr = (int*)     carve((size_t)(NN + 1) * 4);
    int2*     sorted  = (int2*)    carve((size_t)NE * 8);
    float*    xagg    = (float*)   carve((size_t)NN * 64 * 4);
    (void)ws_size; (void)in_sizes; (void)n_in; (void)out_size;

    hipMemsetAsync(hist, 0, (size_t)NN * 8, stream);
    k_hist<<<(NE + 255) / 256, 256, 0, stream>>>(ei, ew, hist, posbuf, NE);
    k_scan<<<1, 1024, 0, stream>>>(hist, dinv, row_ptr, NN);
    k_scatter<<<(NE + 255) / 256, 256, 0, stream>>>(ei, ew, dinv, row_ptr, posbuf, sorted, NE);
    k_agg<<<(NN + 3) / 4, 256, 0, stream>>>(x, dinv, row_ptr, sorted, xagg, NN);
    k_gemm<<<NN / 16, 128, 0, stream>>>(xagg, (const float4*)W, (const float4*)b,
                                        out, NN);
}

// Round 5
// 197.213 us; speedup vs baseline: 1.4993x; 1.0011x over previous
//
#include <hip/hip_runtime.h>

#define NN 50000
#define NE 800000
// K=8, D_IN=64, D_OUT=64 hard-coded below

typedef float v4f __attribute__((ext_vector_type(4)));
typedef unsigned long long u64;

#define FXS 33554432.0f          // 2^25 fixed-point scale for edge weights
#define FXI (1.0f / 33554432.0f)

__global__ void k_zero(u64* __restrict__ hist, int n) {
    int i = blockIdx.x * blockDim.x + threadIdx.x;
    if (i < n) hist[i] = 0ULL;
}

// One packed u64 atomic per edge: bits [40..63] = count, bits [0..39] = sum(ew)
// in 2^-25 fixed point (max node weight-sum ~50 << 2^15, no overflow).
// Return value gives this edge's position within its dst group -> no cursor
// atomic needed in k_scatter.
__global__ void k_hist(const int* __restrict__ ei, const float* __restrict__ ew,
                       u64* __restrict__ hist, unsigned* __restrict__ posbuf, int E) {
    int e = blockIdx.x * blockDim.x + threadIdx.x;
    if (e < E) {
        int d = ei[E + e];
        unsigned fx = (unsigned)(ew[e] * FXS + 0.5f);
        u64 old = atomicAdd(&hist[d], ((u64)1 << 40) | (u64)fx);
        posbuf[e] = (unsigned)(old >> 40);
    }
}

// Single block, 1024 threads. Exclusive scan of counts -> row_ptr, and
// dinv = rsqrt(1 + fixed_point_sum) (self-loop weight 1 folded in here).
__global__ void k_scan(const u64* __restrict__ hist, float* __restrict__ dinv,
                       int* __restrict__ row_ptr, int n) {
    __shared__ int wsum[16];
    __shared__ int woff[16];
    __shared__ int stot;
    int tid  = threadIdx.x;
    int lane = tid & 63;
    int wid  = tid >> 6;
    int run = 0;
    for (int base = 0; base < n; base += 4096) {
        int i0 = base + tid * 4;
        int v[4];
#pragma unroll
        for (int j = 0; j < 4; j++) {
            int i = i0 + j;
            v[j] = 0;
            if (i < n) {
                u64 h = hist[i];
                v[j] = (int)(h >> 40);
                float deg = 1.0f + (float)(h & 0xFFFFFFFFFFULL) * FXI;
                dinv[i] = rsqrtf(deg);
            }
        }
        int s = v[0] + v[1] + v[2] + v[3];
        int incl = s;
#pragma unroll
        for (int off = 1; off < 64; off <<= 1) {
            int t = __shfl_up(incl, off, 64);
            if (lane >= off) incl += t;
        }
        if (lane == 63) wsum[wid] = incl;
        __syncthreads();
        if (tid == 0) {
            int a = 0;
            for (int w = 0; w < 16; w++) { woff[w] = a; a += wsum[w]; }
            stot = a;
        }
        __syncthreads();
        int excl = run + woff[wid] + (incl - s);
#pragma unroll
        for (int j = 0; j < 4; j++) {
            int i = i0 + j;
            if (i < n) row_ptr[i] = excl;
            excl += v[j];
        }
        run += stot;
        __syncthreads();   // protect wsum/stot before next chunk
    }
    if (tid == 0) row_ptr[n] = run;
}

// Atomic-free scatter: position comes from k_hist's atomic return value.
__global__ void k_scatter(const int* __restrict__ ei, const float* __restrict__ ew,
                          const float* __restrict__ dinv, const int* __restrict__ row_ptr,
                          const unsigned* __restrict__ posbuf,
                          int2* __restrict__ sorted, int E) {
    int e = blockIdx.x * blockDim.x + threadIdx.x;
    if (e < E) {
        int s = ei[e];
        int d = ei[E + e];
        float nrm = dinv[s] * ew[e] * dinv[d];
        int pos = row_ptr[d] + (int)posbuf[e];
        sorted[pos] = make_int2(s, __float_as_int(nrm));
    }
}

// One wave per node; lane = channel. xagg[n,:] = dinv^2 * x[n,:] + sum norm*x[src,:]
// 8-deep predicated unroll: 8 edge-record loads then 8 independent row gathers
// in flight per iteration -> breaks the serial dependent-load chain.
__global__ __launch_bounds__(256) void k_agg(const float* __restrict__ x,
                                             const float* __restrict__ dinv,
                                             const int* __restrict__ row_ptr,
                                             const int2* __restrict__ sorted,
                                             float* __restrict__ xagg, int n) {
    int node = blockIdx.x * 4 + (threadIdx.x >> 6);
    if (node >= n) return;
    int lane = threadIdx.x & 63;
    float di = dinv[node];
    float a[8];
    a[0] = di * di * x[((unsigned)node << 6) + lane];
#pragma unroll
    for (int j = 1; j < 8; j++) a[j] = 0.f;
    int beg = row_ptr[node], end = row_ptr[node + 1];
    for (int i = beg; i < end; i += 8) {
        int   si[8];
        float w[8];
#pragma unroll
        for (int j = 0; j < 8; j++) {
            int idx = (i + j < end) ? (i + j) : beg;   // safe clamp (beg<end here)
            int2 p = sorted[idx];
            si[j] = p.x;
            w[j]  = (i + j < end) ? __int_as_float(p.y) : 0.f;
        }
#pragma unroll
        for (int j = 0; j < 8; j++) {
            a[j] += w[j] * x[((unsigned)si[j] << 6) + lane];
        }
    }
    float acc = ((a[0] + a[1]) + (a[2] + a[3])) + ((a[4] + a[5]) + (a[6] + a[7]));
    xagg[((unsigned)node << 6) + lane] = acc;
}

// out[n,k,:] = xagg[n,:] @ W[k] + b[k].  16 nodes per 128-thread block,
// register-blocked over nodes; float4 W loads, non-temporal output stores
// (output stream is never re-read -> don't pollute L2).
__global__ __launch_bounds__(128) void k_gemm(const float* __restrict__ xagg,
                                              const float4* __restrict__ W4,
                                              const float4* __restrict__ b4,
                                              float* __restrict__ out, int n) {
    __shared__ float xs[16][64];
    int t  = threadIdx.x;          // 0..127
    int n0 = blockIdx.x * 16;
    const float4* xg = (const float4*)(xagg + (size_t)n0 * 64);
    float4* xsv = (float4*)&xs[0][0];
    xsv[t]       = xg[t];
    xsv[t + 128] = xg[t + 128];
    __syncthreads();
    int k = t >> 4;       // 0..7
    int q = t & 15;       // output float4 column within head
    float4 bias = b4[k * 16 + q];
    float4 acc[16];
#pragma unroll
    for (int nn = 0; nn < 16; nn++) acc[nn] = bias;
    for (int c = 0; c < 64; c++) {
        float4 w = W4[(size_t)k * 1024 + c * 16 + q];
#pragma unroll
        for (int nn = 0; nn < 16; nn++) {
            float a = xs[nn][c];
            acc[nn].x += a * w.x;
            acc[nn].y += a * w.y;
            acc[nn].z += a * w.z;
            acc[nn].w += a * w.w;
        }
    }
#pragma unroll
    for (int nn = 0; nn < 16; nn++) {
        v4f v = { acc[nn].x, acc[nn].y, acc[nn].z, acc[nn].w };
        v4f* dst = (v4f*)(out + (((size_t)(n0 + nn) * 8 + k) * 16 + q) * 4);
        __builtin_nontemporal_store(v, dst);
    }
}

extern "C" void kernel_launch(void* const* d_in, const int* in_sizes, int n_in,
                              void* d_out, int out_size, void* d_ws, size_t ws_size,
                              hipStream_t stream) {
    const float* x  = (const float*)d_in[0];
    const int*   ei = (const int*)d_in[1];     // [2, E] int32: src row then dst row
    const float* ew = (const float*)d_in[2];
    const float* W  = (const float*)d_in[3];   // [8,64,64]
    const float* b  = (const float*)d_in[4];   // [8,64]
    float* out = (float*)d_out;

    char* ws = (char*)d_ws;
    size_t off = 0;
    auto carve = [&](size_t bytes) {
        void* p = ws + off;
        off += (bytes + 255) & ~(size_t)255;
        return p;
    };
    u64*      hist    = (u64*)     carve((size_t)NN * 8);
    unsigned* posbuf  = (unsigned*)carve((size_t)NE * 4);
    float*    dinv    = (float*)   carve((size_t)NN * 4);
    int*      row_ptr = (int*)     carve((size_t)(NN + 1) * 4);
    int2*     sorted  = (int2*)    carve((size_t)NE * 8);
    float*    xagg    = (float*)   carve((size_t)NN * 64 * 4);
    (void)ws_size; (void)in_sizes; (void)n_in; (void)out_size;

    k_zero<<<(NN + 255) / 256, 256, 0, stream>>>(hist, NN);
    k_hist<<<(NE + 255) / 256, 256, 0, stream>>>(ei, ew, hist, posbuf, NE);
    k_scan<<<1, 1024, 0, stream>>>(hist, dinv, row_ptr, NN);
    k_scatter<<<(NE + 255) / 256, 256, 0, stream>>>(ei, ew, dinv, row_ptr, posbuf, sorted, NE);
    k_agg<<<(NN + 3) / 4, 256, 0, stream>>>(x, dinv, row_ptr, sorted, xagg, NN);
    k_gemm<<<NN / 16, 128, 0, stream>>>(xagg, (const float4*)W, (const float4*)b,
                                        out, NN);
}